// Round 1
// baseline (112.295 us; speedup 1.0000x reference)
//
#include <hip/hip_runtime.h>
#include <math.h>

// JAX >= 0.5.0 defaults jax_threefry_partitionable=True. If output 1 (path
// indices) mismatches, flip this to 0 (legacy split/random_bits layout).
#define JAX_THREEFRY_PARTITIONABLE 1

__device__ __forceinline__ unsigned rotl32(unsigned x, int d) {
    return (x << d) | (x >> (32 - d));
}

// JAX threefry2x32: 5 groups of 4 rounds, key injection after each group.
__device__ void threefry2x32(unsigned k0, unsigned k1, unsigned x0, unsigned x1,
                             unsigned& o0, unsigned& o1) {
    unsigned k2 = k0 ^ k1 ^ 0x1BD11BDAu;
    unsigned v0 = x0 + k0, v1 = x1 + k1;
    const int ra[4] = {13, 15, 26, 6};
    const int rb[4] = {17, 29, 16, 24};
#pragma unroll
    for (int i = 0; i < 4; i++) { v0 += v1; v1 = rotl32(v1, ra[i]); v1 ^= v0; }
    v0 += k1; v1 += k2 + 1u;
#pragma unroll
    for (int i = 0; i < 4; i++) { v0 += v1; v1 = rotl32(v1, rb[i]); v1 ^= v0; }
    v0 += k2; v1 += k0 + 2u;
#pragma unroll
    for (int i = 0; i < 4; i++) { v0 += v1; v1 = rotl32(v1, ra[i]); v1 ^= v0; }
    v0 += k0; v1 += k1 + 3u;
#pragma unroll
    for (int i = 0; i < 4; i++) { v0 += v1; v1 = rotl32(v1, rb[i]); v1 ^= v0; }
    v0 += k1; v1 += k2 + 4u;
#pragma unroll
    for (int i = 0; i < 4; i++) { v0 += v1; v1 = rotl32(v1, ra[i]); v1 ^= v0; }
    v0 += k2; v1 += k0 + 5u;
    o0 = v0; o1 = v1;
}

__global__ void __launch_bounds__(64)
node2vec_fused(const float* __restrict__ x,
               const float* __restrict__ fc1_w, const float* __restrict__ fc1_b,
               const float* __restrict__ fc2_w, const float* __restrict__ fc2_b,
               const float* __restrict__ fc3_w, const float* __restrict__ fc3_b,
               const float* __restrict__ pw,   const float* __restrict__ pb,
               float* __restrict__ out) {
    const int tid = threadIdx.x;
    __shared__ float xs[6 * 32];
    __shared__ float h1[6 * 64];
    __shared__ float h2[6 * 32];
    __shared__ float lp[6 * 6];

    // stage x [6,32] in LDS
    for (int i = tid; i < 192; i += 64) xs[i] = x[i];
    __syncthreads();

    // h1 = relu(x @ fc1_w + fc1_b): thread tid owns column j=tid for all 6 rows
    {
        const int j = tid;
        float acc[6];
#pragma unroll
        for (int n = 0; n < 6; n++) acc[n] = fc1_b[j];
        for (int k = 0; k < 32; k++) {
            float w = fc1_w[k * 64 + j];
#pragma unroll
            for (int n = 0; n < 6; n++) acc[n] = fmaf(xs[n * 32 + k], w, acc[n]);
        }
#pragma unroll
        for (int n = 0; n < 6; n++) h1[n * 64 + j] = fmaxf(acc[n], 0.0f);
    }
    __syncthreads();

    // h2 = relu(h1 @ fc2_w + fc2_b): 192 outputs, 3 per thread
#pragma unroll
    for (int r = 0; r < 3; r++) {
        int idx = tid + 64 * r;
        int n = idx >> 5, j = idx & 31;
        float acc = fc2_b[j];
        for (int k = 0; k < 64; k++) acc = fmaf(h1[n * 64 + k], fc2_w[k * 32 + j], acc);
        h2[idx] = fmaxf(acc, 0.0f);
    }
    // logits = x @ path_fc_w + path_fc_b (6x6), threads 0..35
    if (tid < 36) {
        int n = tid / 6, j = tid % 6;
        float acc = pb[j];
        for (int k = 0; k < 32; k++) acc = fmaf(xs[n * 32 + k], pw[k * 6 + j], acc);
        lp[n * 6 + j] = acc;
    }
    __syncthreads();

    // energy = softplus(h2 @ fc3_w + fc3_b) = logaddexp(z, 0)
    if (tid < 6) {
        float acc = fc3_b[0];
        for (int k = 0; k < 32; k++) acc = fmaf(h2[tid * 32 + k], fc3_w[k], acc);
        out[tid] = fmaxf(acc, 0.0f) + log1pf(expf(-fabsf(acc)));
    }

    // log_softmax over each row of lp
    if (tid < 6) {
        float m = lp[tid * 6 + 0];
        for (int j = 1; j < 6; j++) m = fmaxf(m, lp[tid * 6 + j]);
        float s = 0.0f;
        float sh[6];
        for (int j = 0; j < 6; j++) { sh[j] = lp[tid * 6 + j] - m; s += expf(sh[j]); }
        float ls = logf(s);
        for (int j = 0; j < 6; j++) lp[tid * 6 + j] = sh[j] - ls;
    }
    __syncthreads();

    // Sequential gumbel-argmax sampling, replicating jax.random exactly.
    if (tid == 0) {
        unsigned keyA[5], keyB[5];
#if JAX_THREEFRY_PARTITIONABLE
        // split(key(42), 5): key_t = threefry((0,42), (hi=0, lo=t))
        for (int t = 0; t < 5; t++)
            threefry2x32(0u, 42u, 0u, (unsigned)t, keyA[t], keyB[t]);
#else
        // legacy split: counts = iota(10), halves (0..4),(5..9); reshape(5,2)
        unsigned C[10];
        for (int i = 0; i < 5; i++) {
            unsigned a, b;
            threefry2x32(0u, 42u, (unsigned)i, (unsigned)(i + 5), a, b);
            C[i] = a; C[i + 5] = b;
        }
        for (int t = 0; t < 5; t++) { keyA[t] = C[2 * t]; keyB[t] = C[2 * t + 1]; }
#endif
        bool mask[6] = {false, true, true, true, true, true};
        int cur = 0;
        const float tiny = 1.1754943508222875e-38f;  // finfo(f32).tiny
        out[6] = 0.0f;
        for (int t = 0; t < 5; t++) {
            unsigned bits[6];
#if JAX_THREEFRY_PARTITIONABLE
            // bits[i] = o0 ^ o1 of threefry(key, (hi=0, lo=i))
            for (int i = 0; i < 6; i++) {
                unsigned a, b;
                threefry2x32(keyA[t], keyB[t], 0u, (unsigned)i, a, b);
                bits[i] = a ^ b;
            }
#else
            // legacy: counts iota(6) halves (0..2),(3..5); concat outputs
            for (int i = 0; i < 3; i++) {
                unsigned a, b;
                threefry2x32(keyA[t], keyB[t], (unsigned)i, (unsigned)(i + 3), a, b);
                bits[i] = a; bits[i + 3] = b;
            }
#endif
            float best = -INFINITY;
            int bi = 0;
            for (int i = 0; i < 6; i++) {
                // uniform(key,(6,),minval=tiny,maxval=1)
                float u = __uint_as_float((bits[i] >> 9) | 0x3f800000u) - 1.0f;
                u = u * (1.0f - tiny) + tiny;
                u = fmaxf(tiny, u);
                float g = -logf(-logf(u));  // gumbel
                float s = mask[i] ? (lp[cur * 6 + i] + g) : -INFINITY;
                if (s > best) { best = s; bi = i; }  // first-max like jnp.argmax
            }
            cur = bi;
            mask[cur] = false;
            out[7 + t] = (float)cur;
        }
        out[12] = 0.0f;
    }
}

extern "C" void kernel_launch(void* const* d_in, const int* in_sizes, int n_in,
                              void* d_out, int out_size, void* d_ws, size_t ws_size,
                              hipStream_t stream) {
    const float* x     = (const float*)d_in[0];
    // d_in[1] = path (int32) — computed-but-unused gather in the reference
    const float* fc1_w = (const float*)d_in[2];
    const float* fc1_b = (const float*)d_in[3];
    const float* fc2_w = (const float*)d_in[4];
    const float* fc2_b = (const float*)d_in[5];
    const float* fc3_w = (const float*)d_in[6];
    const float* fc3_b = (const float*)d_in[7];
    const float* pw    = (const float*)d_in[8];
    const float* pb    = (const float*)d_in[9];
    float* out = (float*)d_out;

    hipLaunchKernelGGL(node2vec_fused, dim3(1), dim3(64), 0, stream,
                       x, fc1_w, fc1_b, fc2_w, fc2_b, fc3_w, fc3_b, pw, pb, out);
}

// Round 2
// 79.514 us; speedup vs baseline: 1.4123x; 1.4123x over previous
//
#include <hip/hip_runtime.h>
#include <math.h>

__device__ __forceinline__ unsigned rotl32(unsigned x, int d) {
    return (x << d) | (x >> (32 - d));
}

// JAX threefry2x32: 5 groups of 4 rounds, key injection after each group.
__device__ void threefry2x32(unsigned k0, unsigned k1, unsigned x0, unsigned x1,
                             unsigned& o0, unsigned& o1) {
    unsigned k2 = k0 ^ k1 ^ 0x1BD11BDAu;
    unsigned v0 = x0 + k0, v1 = x1 + k1;
    const int ra[4] = {13, 15, 26, 6};
    const int rb[4] = {17, 29, 16, 24};
#pragma unroll
    for (int i = 0; i < 4; i++) { v0 += v1; v1 = rotl32(v1, ra[i]); v1 ^= v0; }
    v0 += k1; v1 += k2 + 1u;
#pragma unroll
    for (int i = 0; i < 4; i++) { v0 += v1; v1 = rotl32(v1, rb[i]); v1 ^= v0; }
    v0 += k2; v1 += k0 + 2u;
#pragma unroll
    for (int i = 0; i < 4; i++) { v0 += v1; v1 = rotl32(v1, ra[i]); v1 ^= v0; }
    v0 += k0; v1 += k1 + 3u;
#pragma unroll
    for (int i = 0; i < 4; i++) { v0 += v1; v1 = rotl32(v1, rb[i]); v1 ^= v0; }
    v0 += k1; v1 += k2 + 4u;
#pragma unroll
    for (int i = 0; i < 4; i++) { v0 += v1; v1 = rotl32(v1, ra[i]); v1 ^= v0; }
    v0 += k2; v1 += k0 + 5u;
    o0 = v0; o1 = v1;
}

__global__ void __launch_bounds__(64)
node2vec_fused(const float* __restrict__ x,
               const float* __restrict__ fc1_w, const float* __restrict__ fc1_b,
               const float* __restrict__ fc2_w, const float* __restrict__ fc2_b,
               const float* __restrict__ fc3_w, const float* __restrict__ fc3_b,
               const float* __restrict__ pw,   const float* __restrict__ pb,
               float* __restrict__ out) {
    const int tid = threadIdx.x;
    __shared__ float sw1[2048];   // fc1_w [32,64]
    __shared__ float sw2[2048];   // fc2_w [64,32]
    __shared__ float sxs[192];    // x [6,32]
    __shared__ float spw[192];    // path_fc_w [32,6]
    __shared__ float sb1[64];
    __shared__ float sb2[32];
    __shared__ float sw3[32];
    __shared__ float spb[8];
    __shared__ float sgs[32];     // 30 gumbel values
    __shared__ float sb3;
    __shared__ float h1[384];     // [6,64]
    __shared__ float h2[192];     // [6,32]
    __shared__ float lp[36];      // [6,6]

    // ---- Phase 0: issue ALL global loads up front (one memory round-trip) ----
    float4 r_w1[8], r_w2[8];
    {
        const float4* f4 = (const float4*)fc1_w;
#pragma unroll
        for (int r = 0; r < 8; r++) r_w1[r] = f4[tid + 64 * r];
    }
    {
        const float4* f4 = (const float4*)fc2_w;
#pragma unroll
        for (int r = 0; r < 8; r++) r_w2[r] = f4[tid + 64 * r];
    }
    float4 r_x  = make_float4(0.f, 0.f, 0.f, 0.f);
    float4 r_pw = make_float4(0.f, 0.f, 0.f, 0.f);
    if (tid < 48) { r_x = ((const float4*)x)[tid]; r_pw = ((const float4*)pw)[tid]; }
    float r_b1 = fc1_b[tid];
    float r_small = 0.f;   // tid<32: fc2_b[tid]; tid>=32: fc3_w[tid-32]
    if (tid < 32) r_small = fc2_b[tid]; else r_small = fc3_w[tid - 32];
    float r_pb = (tid < 6) ? pb[tid] : 0.f;
    float r_b3 = (tid == 0) ? fc3_b[0] : 0.f;

    // ---- Gumbel table (input-independent) — ALU work overlapping the loads ----
    if (tid < 30) {
        int t = tid / 6;
        int i = tid - t * 6;
        unsigned ka, kb, a, b;
        threefry2x32(0u, 42u, 0u, (unsigned)t, ka, kb);   // split(key(42),5)[t]
        threefry2x32(ka, kb, 0u, (unsigned)i, a, b);      // random_bits, partitionable
        unsigned bits = a ^ b;
        const float tiny = 1.1754943508222875e-38f;
        float u = __uint_as_float((bits >> 9) | 0x3f800000u) - 1.0f;
        u = u * (1.0f - tiny) + tiny;
        u = fmaxf(tiny, u);
        sgs[tid] = -logf(-logf(u));                       // gumbel
    }

    // ---- Spill staged data to LDS ----
#pragma unroll
    for (int r = 0; r < 8; r++) ((float4*)sw1)[tid + 64 * r] = r_w1[r];
#pragma unroll
    for (int r = 0; r < 8; r++) ((float4*)sw2)[tid + 64 * r] = r_w2[r];
    if (tid < 48) { ((float4*)sxs)[tid] = r_x; ((float4*)spw)[tid] = r_pw; }
    sb1[tid] = r_b1;
    if (tid < 32) sb2[tid] = r_small; else sw3[tid - 32] = r_small;
    if (tid < 6) spb[tid] = r_pb;
    if (tid == 0) sb3 = r_b3;
    __syncthreads();

    // ---- h1 = relu(x @ fc1_w + b1): thread tid owns column j=tid, all 6 rows ----
    {
        const int j = tid;
        float acc[6];
#pragma unroll
        for (int n = 0; n < 6; n++) acc[n] = sb1[j];
#pragma unroll
        for (int k = 0; k < 32; k++) {
            float w = sw1[k * 64 + j];
#pragma unroll
            for (int n = 0; n < 6; n++) acc[n] = fmaf(sxs[n * 32 + k], w, acc[n]);
        }
#pragma unroll
        for (int n = 0; n < 6; n++) h1[n * 64 + j] = fmaxf(acc[n], 0.0f);
    }
    __syncthreads();

    // ---- h2 = relu(h1 @ fc2_w + b2): 192 outputs, 3 per thread ----
#pragma unroll
    for (int r = 0; r < 3; r++) {
        int idx = tid + 64 * r;
        int n = idx >> 5, j = idx & 31;
        float acc = sb2[j];
#pragma unroll
        for (int k = 0; k < 64; k++) acc = fmaf(h1[n * 64 + k], sw2[k * 32 + j], acc);
        h2[idx] = fmaxf(acc, 0.0f);
    }
    // ---- logits = x @ path_fc_w + pb (6x6), threads 0..35 ----
    if (tid < 36) {
        int n = tid / 6, j = tid - (tid / 6) * 6;
        float acc = spb[j];
#pragma unroll
        for (int k = 0; k < 32; k++) acc = fmaf(sxs[n * 32 + k], spw[k * 6 + j], acc);
        lp[n * 6 + j] = acc;
    }
    __syncthreads();

    // ---- energy = softplus(h2 @ fc3_w + b3), threads 0..5 ----
    if (tid < 6) {
        float acc = sb3;
#pragma unroll
        for (int k = 0; k < 32; k++) acc = fmaf(h2[tid * 32 + k], sw3[k], acc);
        out[tid] = fmaxf(acc, 0.0f) + log1pf(expf(-fabsf(acc)));
    }
    // ---- log_softmax rows on threads 8..13 (parallel with softplus) ----
    if (tid >= 8 && tid < 14) {
        int n = tid - 8;
        float m = lp[n * 6 + 0];
        for (int j = 1; j < 6; j++) m = fmaxf(m, lp[n * 6 + j]);
        float s = 0.0f, sh[6];
        for (int j = 0; j < 6; j++) { sh[j] = lp[n * 6 + j] - m; s += expf(sh[j]); }
        float ls = logf(s);
        for (int j = 0; j < 6; j++) lp[n * 6 + j] = sh[j] - ls;
    }
    __syncthreads();

    // ---- sequential masked gumbel-argmax: now just 5 x (6 adds + compare) ----
    if (tid == 0) {
        bool mask[6] = {false, true, true, true, true, true};
        int cur = 0;
        out[6] = 0.0f;
        for (int t = 0; t < 5; t++) {
            float best = -INFINITY;
            int bi = 0;
#pragma unroll
            for (int i = 0; i < 6; i++) {
                float s = mask[i] ? (lp[cur * 6 + i] + sgs[t * 6 + i]) : -INFINITY;
                if (s > best) { best = s; bi = i; }   // first-max like jnp.argmax
            }
            cur = bi;
            mask[cur] = false;
            out[7 + t] = (float)cur;
        }
        out[12] = 0.0f;
    }
}

extern "C" void kernel_launch(void* const* d_in, const int* in_sizes, int n_in,
                              void* d_out, int out_size, void* d_ws, size_t ws_size,
                              hipStream_t stream) {
    const float* x     = (const float*)d_in[0];
    // d_in[1] = path (int32) — computed-but-unused gather in the reference
    const float* fc1_w = (const float*)d_in[2];
    const float* fc1_b = (const float*)d_in[3];
    const float* fc2_w = (const float*)d_in[4];
    const float* fc2_b = (const float*)d_in[5];
    const float* fc3_w = (const float*)d_in[6];
    const float* fc3_b = (const float*)d_in[7];
    const float* pw    = (const float*)d_in[8];
    const float* pb    = (const float*)d_in[9];
    float* out = (float*)d_out;

    hipLaunchKernelGGL(node2vec_fused, dim3(1), dim3(64), 0, stream,
                       x, fc1_w, fc1_b, fc2_w, fc2_b, fc3_w, fc3_b, pw, pb, out);
}

// Round 3
// 76.140 us; speedup vs baseline: 1.4749x; 1.0443x over previous
//
#include <hip/hip_runtime.h>
#include <math.h>

// Intra-wave LDS produce->consume sync: drain LDS ops + block compiler reordering.
// Waves are lockstep on CDNA, so no s_barrier needed for same-wave communication.
#define WAVE_SYNC() do { asm volatile("s_waitcnt lgkmcnt(0)" ::: "memory"); \
                         __builtin_amdgcn_wave_barrier(); } while (0)

__device__ __forceinline__ unsigned rotl32(unsigned x, int d) {
    return (x << d) | (x >> (32 - d));
}

// JAX threefry2x32: 5 groups of 4 rounds, key injection after each group.
__device__ void threefry2x32(unsigned k0, unsigned k1, unsigned x0, unsigned x1,
                             unsigned& o0, unsigned& o1) {
    unsigned k2 = k0 ^ k1 ^ 0x1BD11BDAu;
    unsigned v0 = x0 + k0, v1 = x1 + k1;
    const int ra[4] = {13, 15, 26, 6};
    const int rb[4] = {17, 29, 16, 24};
#pragma unroll
    for (int i = 0; i < 4; i++) { v0 += v1; v1 = rotl32(v1, ra[i]); v1 ^= v0; }
    v0 += k1; v1 += k2 + 1u;
#pragma unroll
    for (int i = 0; i < 4; i++) { v0 += v1; v1 = rotl32(v1, rb[i]); v1 ^= v0; }
    v0 += k2; v1 += k0 + 2u;
#pragma unroll
    for (int i = 0; i < 4; i++) { v0 += v1; v1 = rotl32(v1, ra[i]); v1 ^= v0; }
    v0 += k0; v1 += k1 + 3u;
#pragma unroll
    for (int i = 0; i < 4; i++) { v0 += v1; v1 = rotl32(v1, rb[i]); v1 ^= v0; }
    v0 += k1; v1 += k2 + 4u;
#pragma unroll
    for (int i = 0; i < 4; i++) { v0 += v1; v1 = rotl32(v1, ra[i]); v1 ^= v0; }
    v0 += k2; v1 += k0 + 5u;
    o0 = v0; o1 = v1;
}

// 4 waves, zero workgroup barriers:
//   wave 0   : path branch (logits -> log_softmax -> gumbel-argmax sampling)
//   waves 1-3: energy MLP, wave w owns rows {w-1, w+2} end-to-end; all
//              cross-lane data flow stays inside the wave (per-wave LDS copies).
__global__ void __launch_bounds__(256)
node2vec_fused(const float* __restrict__ x,
               const float* __restrict__ fc1_w, const float* __restrict__ fc1_b,
               const float* __restrict__ fc2_w, const float* __restrict__ fc2_b,
               const float* __restrict__ fc3_w, const float* __restrict__ fc3_b,
               const float* __restrict__ pw,   const float* __restrict__ pb,
               float* __restrict__ out) {
    const int tid = threadIdx.x;
    const int wv  = tid >> 6;
    const int l   = tid & 63;

    __shared__ float sxs[192];        // x for wave 0
    __shared__ float spw[192];        // path_fc_w
    __shared__ float lp[36];          // logits -> log_probs
    __shared__ float sgs[30];         // gumbel table
    __shared__ float sxe[3][192];     // per-energy-wave private copy of x
    __shared__ float sh1[3][2][64];   // per-energy-wave h1 rows {w, w+3}

    if (wv == 0) {
        // ---------------- path branch (bitwise-identical to R2) ----------------
        if (l < 48) {
            ((float4*)sxs)[l] = ((const float4*)x)[l];
            ((float4*)spw)[l] = ((const float4*)pw)[l];
        }
        int n = 0, j = 0;
        float pbj = 0.f;
        if (l < 36) { n = l / 6; j = l - n * 6; pbj = pb[j]; }
        if (l < 30) {   // gumbel table: input-independent, overlaps the loads
            int t = l / 6, i = l - t * 6;
            unsigned ka, kb, a, b;
            threefry2x32(0u, 42u, 0u, (unsigned)t, ka, kb);  // split(key(42),5)[t]
            threefry2x32(ka, kb, 0u, (unsigned)i, a, b);     // partitionable bits
            unsigned bits = a ^ b;
            const float tiny = 1.1754943508222875e-38f;
            float u = __uint_as_float((bits >> 9) | 0x3f800000u) - 1.0f;
            u = u * (1.0f - tiny) + tiny;
            u = fmaxf(tiny, u);
            sgs[l] = -logf(-logf(u));
        }
        WAVE_SYNC();
        if (l < 36) {   // logits = x @ pw + pb
            float acc = pbj;
#pragma unroll
            for (int k = 0; k < 32; k++) acc = fmaf(sxs[n * 32 + k], spw[k * 6 + j], acc);
            lp[n * 6 + j] = acc;
        }
        WAVE_SYNC();
        if (l < 6) {    // row-wise log_softmax
            float m = lp[l * 6 + 0];
            for (int jj = 1; jj < 6; jj++) m = fmaxf(m, lp[l * 6 + jj]);
            float s = 0.0f, sh[6];
            for (int jj = 0; jj < 6; jj++) { sh[jj] = lp[l * 6 + jj] - m; s += expf(sh[jj]); }
            float ls = logf(s);
            for (int jj = 0; jj < 6; jj++) lp[l * 6 + jj] = sh[jj] - ls;
        }
        WAVE_SYNC();
        if (l == 0) {   // sequential masked gumbel-argmax
            bool mask[6] = {false, true, true, true, true, true};
            int cur = 0;
            out[6] = 0.0f;
            for (int t = 0; t < 5; t++) {
                float best = -INFINITY;
                int bi = 0;
#pragma unroll
                for (int i = 0; i < 6; i++) {
                    float s = mask[i] ? (lp[cur * 6 + i] + sgs[t * 6 + i]) : -INFINITY;
                    if (s > best) { best = s; bi = i; }   // first-max like jnp.argmax
                }
                cur = bi;
                mask[cur] = false;
                out[7 + t] = (float)cur;
            }
            out[12] = 0.0f;
        }
    } else {
        // ---------------- energy branch: wave w owns rows {w, w+3} ----------------
        const int w = wv - 1;              // 0..2
        if (l < 48) ((float4*)sxe[w])[l] = ((const float4*)x)[l];
        // weight columns straight into registers (issue everything up front)
        float w1c[32];
#pragma unroll
        for (int k = 0; k < 32; k++) w1c[k] = fc1_w[k * 64 + l];
        float w2c[64];
#pragma unroll
        for (int k = 0; k < 64; k++) w2c[k] = fc2_w[k * 32 + (l & 31)];
        float b1 = fc1_b[l];
        float b2 = fc2_b[l & 31];
        float w3 = fc3_w[l & 31];
        float b3 = fc3_b[0];
        WAVE_SYNC();   // x staged in this wave's private copy

        // h1[w][l], h1[w+3][l]: dot(x_row, fc1_w[:,l]) + b1, relu
        float a0 = b1, a1 = b1;
        const float4* xr = (const float4*)&sxe[w][0];
#pragma unroll
        for (int q = 0; q < 8; q++) {
            float4 v0 = xr[w * 8 + q];
            float4 v1 = xr[(w + 3) * 8 + q];
            a0 = fmaf(v0.x, w1c[4 * q + 0], a0); a0 = fmaf(v0.y, w1c[4 * q + 1], a0);
            a0 = fmaf(v0.z, w1c[4 * q + 2], a0); a0 = fmaf(v0.w, w1c[4 * q + 3], a0);
            a1 = fmaf(v1.x, w1c[4 * q + 0], a1); a1 = fmaf(v1.y, w1c[4 * q + 1], a1);
            a1 = fmaf(v1.z, w1c[4 * q + 2], a1); a1 = fmaf(v1.w, w1c[4 * q + 3], a1);
        }
        sh1[w][0][l] = fmaxf(a0, 0.0f);
        sh1[w][1][l] = fmaxf(a1, 0.0f);
        WAVE_SYNC();

        // h2: half 0 (lanes 0-31) -> row w, half 1 -> row w+3; column j2 = l&31
        const int half = l >> 5;
        const float4* hr = (const float4*)&sh1[w][half][0];
        float acc = b2;
#pragma unroll
        for (int q = 0; q < 16; q++) {
            float4 hv = hr[q];
            acc = fmaf(hv.x, w2c[4 * q + 0], acc); acc = fmaf(hv.y, w2c[4 * q + 1], acc);
            acc = fmaf(hv.z, w2c[4 * q + 2], acc); acc = fmaf(hv.w, w2c[4 * q + 3], acc);
        }
        float h2v = fmaxf(acc, 0.0f);

        // energy = softplus(dot(h2_row, fc3_w) + b3): half-wave shuffle reduce
        float p = h2v * w3;
#pragma unroll
        for (int off = 16; off >= 1; off >>= 1) p += __shfl_xor(p, off, 32);
        float z = p + b3;
        float e = fmaxf(z, 0.0f) + log1pf(expf(-fabsf(z)));
        if (l == 0)       out[w]     = e;
        else if (l == 32) out[w + 3] = e;
    }
}

extern "C" void kernel_launch(void* const* d_in, const int* in_sizes, int n_in,
                              void* d_out, int out_size, void* d_ws, size_t ws_size,
                              hipStream_t stream) {
    const float* x     = (const float*)d_in[0];
    // d_in[1] = path (int32) — computed-but-unused gather in the reference
    const float* fc1_w = (const float*)d_in[2];
    const float* fc1_b = (const float*)d_in[3];
    const float* fc2_w = (const float*)d_in[4];
    const float* fc2_b = (const float*)d_in[5];
    const float* fc3_w = (const float*)d_in[6];
    const float* fc3_b = (const float*)d_in[7];
    const float* pw    = (const float*)d_in[8];
    const float* pb    = (const float*)d_in[9];
    float* out = (float*)d_out;

    hipLaunchKernelGGL(node2vec_fused, dim3(1), dim3(256), 0, stream,
                       x, fc1_w, fc1_b, fc2_w, fc2_b, fc3_w, fc3_b, pw, pb, out);
}

// Round 4
// 75.745 us; speedup vs baseline: 1.4826x; 1.0052x over previous
//
#include <hip/hip_runtime.h>
#include <math.h>

// Intra-wave LDS produce->consume sync: drain LDS ops + block compiler reordering.
// Waves are lockstep on CDNA, so no s_barrier needed for same-wave communication.
#define WAVE_SYNC() do { asm volatile("s_waitcnt lgkmcnt(0)" ::: "memory"); \
                         __builtin_amdgcn_wave_barrier(); } while (0)

__device__ __forceinline__ unsigned rotl32(unsigned x, int d) {
    return (x << d) | (x >> (32 - d));
}

// JAX threefry2x32: 5 groups of 4 rounds, key injection after each group.
__device__ void threefry2x32(unsigned k0, unsigned k1, unsigned x0, unsigned x1,
                             unsigned& o0, unsigned& o1) {
    unsigned k2 = k0 ^ k1 ^ 0x1BD11BDAu;
    unsigned v0 = x0 + k0, v1 = x1 + k1;
    const int ra[4] = {13, 15, 26, 6};
    const int rb[4] = {17, 29, 16, 24};
#pragma unroll
    for (int i = 0; i < 4; i++) { v0 += v1; v1 = rotl32(v1, ra[i]); v1 ^= v0; }
    v0 += k1; v1 += k2 + 1u;
#pragma unroll
    for (int i = 0; i < 4; i++) { v0 += v1; v1 = rotl32(v1, rb[i]); v1 ^= v0; }
    v0 += k2; v1 += k0 + 2u;
#pragma unroll
    for (int i = 0; i < 4; i++) { v0 += v1; v1 = rotl32(v1, ra[i]); v1 ^= v0; }
    v0 += k0; v1 += k1 + 3u;
#pragma unroll
    for (int i = 0; i < 4; i++) { v0 += v1; v1 = rotl32(v1, rb[i]); v1 ^= v0; }
    v0 += k1; v1 += k2 + 4u;
#pragma unroll
    for (int i = 0; i < 4; i++) { v0 += v1; v1 = rotl32(v1, ra[i]); v1 ^= v0; }
    v0 += k2; v1 += k0 + 5u;
    o0 = v0; o1 = v1;
}

// 4 waves, zero workgroup barriers, minimal LDS:
//   wave 0   : path branch — per-lane direct global loads for logits (no LDS
//              staging), LDS only for lp[36] + gumbel table.
//   waves 1-3: energy MLP, wave w owns rows {w-1, w+2}. x broadcast via
//              v_readlane (no LDS); h1->h2 via one per-wave LDS round trip;
//              h2 k-sum split across half-waves (halves per-lane loads).
__global__ void __launch_bounds__(256)
node2vec_fused(const float* __restrict__ x,
               const float* __restrict__ fc1_w, const float* __restrict__ fc1_b,
               const float* __restrict__ fc2_w, const float* __restrict__ fc2_b,
               const float* __restrict__ fc3_w, const float* __restrict__ fc3_b,
               const float* __restrict__ pw,   const float* __restrict__ pb,
               float* __restrict__ out) {
    const int tid = threadIdx.x;
    const int wv  = tid >> 6;
    const int l   = tid & 63;

    __shared__ float lp[36];          // logits -> log_probs
    __shared__ float sgs[30];         // gumbel table
    __shared__ float sh1[3][2][64];   // per-energy-wave h1 rows {w, w+3}

    if (wv == 0) {
        // ---------------- path branch (indices bitwise-identical to R2/R3) ----
        const int n = l / 6, j = l - (l / 6) * 6;   // row, col for l<36
        float xr[32], pwc[32], pbj = 0.f;
        if (l < 36) {
            // direct global loads: one latency trip, no LDS staging, no sync
#pragma unroll
            for (int k = 0; k < 32; k++) xr[k] = x[n * 32 + k];
#pragma unroll
            for (int k = 0; k < 32; k++) pwc[k] = pw[k * 6 + j];
            pbj = pb[j];
        }
        if (l < 30) {   // gumbel table: input-independent, overlaps the loads
            int t = l / 6, i = l - (l / 6) * 6;
            unsigned ka, kb, a, b;
            threefry2x32(0u, 42u, 0u, (unsigned)t, ka, kb);  // split(key(42),5)[t]
            threefry2x32(ka, kb, 0u, (unsigned)i, a, b);     // partitionable bits
            unsigned bits = a ^ b;
            const float tiny = 1.1754943508222875e-38f;
            float u = __uint_as_float((bits >> 9) | 0x3f800000u) - 1.0f;
            u = u * (1.0f - tiny) + tiny;
            u = fmaxf(tiny, u);
            sgs[l] = -logf(-logf(u));
        }
        if (l == 36) out[6]  = 0.0f;
        if (l == 37) out[12] = 0.0f;
        if (l < 36) {   // logits = x @ pw + pb, same fmaf order as before
            float acc = pbj;
#pragma unroll
            for (int k = 0; k < 32; k++) acc = fmaf(xr[k], pwc[k], acc);
            lp[n * 6 + j] = acc;
        }
        WAVE_SYNC();
        if (l < 6) {    // row-wise log_softmax
            float m = lp[l * 6 + 0];
            for (int jj = 1; jj < 6; jj++) m = fmaxf(m, lp[l * 6 + jj]);
            float s = 0.0f, sh[6];
            for (int jj = 0; jj < 6; jj++) { sh[jj] = lp[l * 6 + jj] - m; s += expf(sh[jj]); }
            float ls = logf(s);
            for (int jj = 0; jj < 6; jj++) lp[l * 6 + jj] = sh[jj] - ls;
        }
        WAVE_SYNC();
        if (l == 0) {   // sequential masked gumbel-argmax
            bool mask[6] = {false, true, true, true, true, true};
            int cur = 0;
            for (int t = 0; t < 5; t++) {
                float best = -INFINITY;
                int bi = 0;
#pragma unroll
                for (int i = 0; i < 6; i++) {
                    float s = mask[i] ? (lp[cur * 6 + i] + sgs[t * 6 + i]) : -INFINITY;
                    if (s > best) { best = s; bi = i; }   // first-max like jnp.argmax
                }
                cur = bi;
                mask[cur] = false;
                out[7 + t] = (float)cur;
            }
        }
    } else {
        // ---------------- energy branch: wave w owns rows {w, w+3} ------------
        const int w    = wv - 1;      // 0..2
        const int c    = l & 31;      // column within 32
        const int half = l >> 5;      // k-half for h2

        // all global loads issued up front: ~70 in flight per lane
        float xv0 = x[w * 32 + c];          // row w, replicated across halves
        float xv1 = x[(w + 3) * 32 + c];    // row w+3
        float w1c[32];
#pragma unroll
        for (int k = 0; k < 32; k++) w1c[k] = fc1_w[k * 64 + l];
        float w2h[32];                      // fc2_w rows [32*half, 32*half+32), col c
#pragma unroll
        for (int k = 0; k < 32; k++) w2h[k] = fc2_w[(32 * half + k) * 32 + c];
        float b1 = fc1_b[l];
        float b2 = fc2_b[c];
        float w3 = fc3_w[c];
        float b3 = fc3_b[0];

        // h1[{w,w+3}][l]: x broadcast via readlane (lane k holds x[row][k]),
        // same fmaf order as R3 -> bit-identical h1
        float a0 = b1, a1 = b1;
#pragma unroll
        for (int k = 0; k < 32; k++) {
            float xk0 = __shfl(xv0, k);   // v_readlane: lanes 0-31 hold row w
            float xk1 = __shfl(xv1, k);
            a0 = fmaf(xk0, w1c[k], a0);
            a1 = fmaf(xk1, w1c[k], a1);
        }
        sh1[w][0][l] = fmaxf(a0, 0.0f);
        sh1[w][1][l] = fmaxf(a1, 0.0f);
        WAVE_SYNC();

        // h2 partial dots: this lane covers k in [32*half, +32) for BOTH rows
        float acc0 = 0.f, acc1 = 0.f;
        const float4* h0r = (const float4*)&sh1[w][0][32 * half];
        const float4* h1r = (const float4*)&sh1[w][1][32 * half];
#pragma unroll
        for (int q = 0; q < 8; q++) {
            float4 v0 = h0r[q], v1 = h1r[q];
            acc0 = fmaf(v0.x, w2h[4 * q + 0], acc0); acc0 = fmaf(v0.y, w2h[4 * q + 1], acc0);
            acc0 = fmaf(v0.z, w2h[4 * q + 2], acc0); acc0 = fmaf(v0.w, w2h[4 * q + 3], acc0);
            acc1 = fmaf(v1.x, w2h[4 * q + 0], acc1); acc1 = fmaf(v1.y, w2h[4 * q + 1], acc1);
            acc1 = fmaf(v1.z, w2h[4 * q + 2], acc1); acc1 = fmaf(v1.w, w2h[4 * q + 3], acc1);
        }
        // combine k-halves across the two half-waves
        acc0 += __shfl_xor(acc0, 32);
        acc1 += __shfl_xor(acc1, 32);
        // lanes 0-31 carry row w, lanes 32-63 carry row w+3
        float h2v = fmaxf(b2 + (half ? acc1 : acc0), 0.0f);

        // energy = softplus(dot(h2_row, fc3_w) + b3): half-wave shuffle reduce
        float p = h2v * w3;
#pragma unroll
        for (int off = 16; off >= 1; off >>= 1) p += __shfl_xor(p, off, 32);
        float z = p + b3;
        float e = fmaxf(z, 0.0f) + log1pf(expf(-fabsf(z)));
        if (l == 0)       out[w]     = e;
        else if (l == 32) out[w + 3] = e;
    }
}

extern "C" void kernel_launch(void* const* d_in, const int* in_sizes, int n_in,
                              void* d_out, int out_size, void* d_ws, size_t ws_size,
                              hipStream_t stream) {
    const float* x     = (const float*)d_in[0];
    // d_in[1] = path (int32) — computed-but-unused gather in the reference
    const float* fc1_w = (const float*)d_in[2];
    const float* fc1_b = (const float*)d_in[3];
    const float* fc2_w = (const float*)d_in[4];
    const float* fc2_b = (const float*)d_in[5];
    const float* fc3_w = (const float*)d_in[6];
    const float* fc3_b = (const float*)d_in[7];
    const float* pw    = (const float*)d_in[8];
    const float* pb    = (const float*)d_in[9];
    float* out = (float*)d_out;

    hipLaunchKernelGGL(node2vec_fused, dim3(1), dim3(256), 0, stream,
                       x, fc1_w, fc1_b, fc2_w, fc2_b, fc3_w, fc3_b, pw, pb, out);
}